// Round 12
// baseline (270.359 us; speedup 1.0000x reference)
//
#include <hip/hip_runtime.h>

#define IN_CH   128
#define HEADS   4
#define OUT_CH  16
#define HID     64
#define NEG_SLOPE 0.2f
#define LOG2E   1.44269504088896340736f

#define LDA 136            // padded LDS row stride in bf16 elems

// counting-sort config: destination ranges of 64 nodes
#define RB      6                  // log2(range size)
#define RSZ     64                 // nodes per destination range
#define NRANGE  1024               // padded range count (782 real for N=50000)
#define SEG     4096               // edges per sort block
// ebuf packing: (dlocal << 16) | src   — src < 2^16, dlocal < 2^6

typedef __attribute__((ext_vector_type(8))) short short8;     // 8 bf16
typedef __attribute__((ext_vector_type(4))) float float4v;    // 4 fp32 acc

__device__ __forceinline__ unsigned short f2bf(float f) {
    unsigned int u = __float_as_uint(f);
    u += 0x7FFFu + ((u >> 16) & 1u);
    return (unsigned short)(u >> 16);
}
__device__ __forceinline__ float bf2f(unsigned short u) {
    return __uint_as_float(((unsigned int)u) << 16);
}

// ---------------------------------------------------------------------------
// Kernel A (fused): blocks [0, nblk_proj) do proj GEMM; the rest histogram
// edge dests per segment into cnt[b][NRANGE]. asrc/adst are PRE-SCALED by
// log2(e) so gather can use native exp2 (identical math).
// ---------------------------------------------------------------------------
__global__ __launch_bounds__(256) void proj_count_kernel(
    const float* __restrict__ x,
    const float* __restrict__ W,
    const float* __restrict__ att_src,
    const float* __restrict__ att_dst,
    unsigned short* __restrict__ proj,   // [N, 64] bf16
    float* __restrict__ asrc,            // scaled by LOG2E
    float* __restrict__ adst,            // scaled by LOG2E
    const int* __restrict__ dst,
    int* __restrict__ cnt,
    int n_nodes, int n_edges, int nblk_proj)
{
    __shared__ unsigned short As[64 * LDA];
    __shared__ unsigned short Bs[64 * LDA];
    __shared__ int lc[NRANGE];

    const int tid = threadIdx.x;

    if (blockIdx.x >= nblk_proj) {
        // ---------------- count role ----------------
        const int b = blockIdx.x - nblk_proj;
        #pragma unroll
        for (int i = tid; i < NRANGE; i += 256) lc[i] = 0;
        __syncthreads();
        const int e0 = b * SEG;
        const int e1 = min(e0 + SEG, n_edges);
        for (int e = e0 + tid * 4; e < e1; e += 1024) {
            if (e + 4 <= e1) {
                const int4 d4 = *(const int4*)(dst + e);
                atomicAdd(&lc[d4.x >> RB], 1);
                atomicAdd(&lc[d4.y >> RB], 1);
                atomicAdd(&lc[d4.z >> RB], 1);
                atomicAdd(&lc[d4.w >> RB], 1);
            } else {
                for (int q = e; q < e1; ++q) atomicAdd(&lc[dst[q] >> RB], 1);
            }
        }
        __syncthreads();
        #pragma unroll
        for (int i = tid; i < NRANGE; i += 256) cnt[b * NRANGE + i] = lc[i];
        return;
    }

    // ---------------- proj role ----------------
    const int n0 = blockIdx.x * 64;

    #pragma unroll
    for (int i = 0; i < 8; ++i) {
        int idx4 = i * 256 + tid;
        int row  = idx4 >> 5;
        int c4   = (idx4 & 31) * 4;
        float4 v = *(const float4*)(W + row * IN_CH + c4);
        ushort4 o;
        o.x = f2bf(v.x); o.y = f2bf(v.y); o.z = f2bf(v.z); o.w = f2bf(v.w);
        *(ushort4*)(&Bs[row * LDA + c4]) = o;
    }
    #pragma unroll
    for (int i = 0; i < 8; ++i) {
        int idx4 = i * 256 + tid;
        int row  = idx4 >> 5;
        int c4   = (idx4 & 31) * 4;
        int n    = n0 + row;
        float4 v = make_float4(0.f, 0.f, 0.f, 0.f);
        if (n < n_nodes) v = *(const float4*)(x + (size_t)n * IN_CH + c4);
        ushort4 o;
        o.x = f2bf(v.x); o.y = f2bf(v.y); o.z = f2bf(v.z); o.w = f2bf(v.w);
        *(ushort4*)(&As[row * LDA + c4]) = o;
    }
    __syncthreads();

    const int w    = tid >> 6;
    const int lane = tid & 63;
    const int l16  = lane & 15;
    const int quad = lane >> 4;

    float4v acc0 = {0.f,0.f,0.f,0.f};
    float4v acc1 = {0.f,0.f,0.f,0.f};
    float4v acc2 = {0.f,0.f,0.f,0.f};
    float4v acc3 = {0.f,0.f,0.f,0.f};

    const unsigned short* arow = &As[(w * 16 + l16) * LDA + quad * 8];
    const unsigned short* b0   = &Bs[( 0 + l16) * LDA + quad * 8];
    const unsigned short* b1   = &Bs[(16 + l16) * LDA + quad * 8];
    const unsigned short* b2   = &Bs[(32 + l16) * LDA + quad * 8];
    const unsigned short* b3   = &Bs[(48 + l16) * LDA + quad * 8];

    #pragma unroll
    for (int k0 = 0; k0 < IN_CH; k0 += 32) {
        short8 a  = *(const short8*)(arow + k0);
        acc0 = __builtin_amdgcn_mfma_f32_16x16x32_bf16(a, *(const short8*)(b0 + k0), acc0, 0, 0, 0);
        acc1 = __builtin_amdgcn_mfma_f32_16x16x32_bf16(a, *(const short8*)(b1 + k0), acc1, 0, 0, 0);
        acc2 = __builtin_amdgcn_mfma_f32_16x16x32_bf16(a, *(const short8*)(b2 + k0), acc2, 0, 0, 0);
        acc3 = __builtin_amdgcn_mfma_f32_16x16x32_bf16(a, *(const short8*)(b3 + k0), acc3, 0, 0, 0);
    }

    const float as0 = att_src[ 0 + l16], ad0 = att_dst[ 0 + l16];
    const float as1 = att_src[16 + l16], ad1 = att_dst[16 + l16];
    const float as2 = att_src[32 + l16], ad2 = att_dst[32 + l16];
    const float as3 = att_src[48 + l16], ad3 = att_dst[48 + l16];

    #pragma unroll
    for (int r = 0; r < 4; ++r) {
        const int n = n0 + w * 16 + quad * 4 + r;
        const bool ok = (n < n_nodes);
        float v0 = acc0[r], v1 = acc1[r], v2 = acc2[r], v3 = acc3[r];
        if (ok) {
            proj[(size_t)n * HID +  0 + l16] = f2bf(v0);
            proj[(size_t)n * HID + 16 + l16] = f2bf(v1);
            proj[(size_t)n * HID + 32 + l16] = f2bf(v2);
            proj[(size_t)n * HID + 48 + l16] = f2bf(v3);
        }
        float s0 = v0 * as0, s1 = v1 * as1, s2 = v2 * as2, s3 = v3 * as3;
        float d0 = v0 * ad0, d1 = v1 * ad1, d2 = v2 * ad2, d3 = v3 * ad3;
        #pragma unroll
        for (int off = 8; off >= 1; off >>= 1) {
            s0 += __shfl_down(s0, off, 16);
            s1 += __shfl_down(s1, off, 16);
            s2 += __shfl_down(s2, off, 16);
            s3 += __shfl_down(s3, off, 16);
            d0 += __shfl_down(d0, off, 16);
            d1 += __shfl_down(d1, off, 16);
            d2 += __shfl_down(d2, off, 16);
            d3 += __shfl_down(d3, off, 16);
        }
        if (ok && l16 == 0) {
            asrc[n * HEADS + 0] = s0 * LOG2E;
            asrc[n * HEADS + 1] = s1 * LOG2E;
            asrc[n * HEADS + 2] = s2 * LOG2E;
            asrc[n * HEADS + 3] = s3 * LOG2E;
            adst[n * HEADS + 0] = d0 * LOG2E;
            adst[n * HEADS + 1] = d1 * LOG2E;
            adst[n * HEADS + 2] = d2 * LOG2E;
            adst[n * HEADS + 3] = d3 * LOG2E;
        }
    }
}

// ---------------------------------------------------------------------------
// Kernel B: colprep — per-range totals (coalesced column sums over cnt) +
// block-wide exclusive scan -> colbase[NRANGE+1]. One block, 1024 threads.
// ---------------------------------------------------------------------------
__global__ __launch_bounds__(1024) void colprep_kernel(
    const int* __restrict__ cnt, int* __restrict__ colbase, int nblk)
{
    __shared__ int wtot[16];
    const int r = threadIdx.x;           // 0..1023 = range id
    int tot = 0;
    for (int b = 0; b < nblk; ++b) tot += cnt[b * NRANGE + r];
    const int lane = r & 63;
    const int wv   = r >> 6;
    int sc = tot;
    #pragma unroll
    for (int o = 1; o < 64; o <<= 1) {
        int u = __shfl_up(sc, o);
        if (lane >= o) sc += u;
    }
    if (lane == 63) wtot[wv] = sc;
    __syncthreads();
    int add = 0;
    for (int w = 0; w < wv; ++w) add += wtot[w];
    colbase[r] = add + sc - tot;         // exclusive
    if (r == NRANGE - 1) colbase[NRANGE] = add + sc;
}

// ---------------------------------------------------------------------------
// Kernel C: bin edges into range-major ebuf, packed (dlocal<<16)|src.
// lpos[c] = colbase[c] + prefix over earlier segment blocks (L2-hot cnt).
// ---------------------------------------------------------------------------
__global__ __launch_bounds__(256) void bin_kernel(
    const int* __restrict__ src, const int* __restrict__ dst,
    const int* __restrict__ cnt, const int* __restrict__ colbase,
    unsigned int* __restrict__ ebuf, int n_edges)
{
    __shared__ int lpos[NRANGE];
    const int b = blockIdx.x;
    const int t = threadIdx.x;

    #pragma unroll
    for (int c = t; c < NRANGE; c += 256) {
        int pre = 0;
        for (int b2 = 0; b2 < b; ++b2) pre += cnt[b2 * NRANGE + c];
        lpos[c] = colbase[c] + pre;
    }
    __syncthreads();

    const int e0 = b * SEG;
    const int e1 = min(e0 + SEG, n_edges);
    for (int e = e0 + t * 4; e < e1; e += 1024) {
        if (e + 4 <= e1) {
            const int4 s4 = *(const int4*)(src + e);
            const int4 d4 = *(const int4*)(dst + e);
            {
                const int slot = atomicAdd(&lpos[d4.x >> RB], 1);
                ebuf[slot] = ((unsigned int)(d4.x & (RSZ - 1)) << 16) | (unsigned int)s4.x;
            }
            {
                const int slot = atomicAdd(&lpos[d4.y >> RB], 1);
                ebuf[slot] = ((unsigned int)(d4.y & (RSZ - 1)) << 16) | (unsigned int)s4.y;
            }
            {
                const int slot = atomicAdd(&lpos[d4.z >> RB], 1);
                ebuf[slot] = ((unsigned int)(d4.z & (RSZ - 1)) << 16) | (unsigned int)s4.z;
            }
            {
                const int slot = atomicAdd(&lpos[d4.w >> RB], 1);
                ebuf[slot] = ((unsigned int)(d4.w & (RSZ - 1)) << 16) | (unsigned int)s4.w;
            }
        } else {
            for (int q = e; q < e1; ++q) {
                const int d = dst[q];
                const int slot = atomicAdd(&lpos[d >> RB], 1);
                ebuf[slot] = ((unsigned int)(d & (RSZ - 1)) << 16) | (unsigned int)src[q];
            }
        }
    }
}

// ---------------------------------------------------------------------------
// Kernel D: per-range (64-node) histogram + single-wave scan + rsdeg write +
// LDS-atomic scatter into the range's csr window. One block per range (782).
// ---------------------------------------------------------------------------
__global__ __launch_bounds__(256) void range_csr_kernel(
    const unsigned int* __restrict__ ebuf, const int* __restrict__ colbase,
    int2* __restrict__ rsdeg, unsigned short* __restrict__ csr, int n_nodes)
{
    __shared__ int hist[RSZ];
    __shared__ int cur[RSZ];

    const int r    = blockIdx.x;
    const int base = r << RB;
    const int lim  = min(RSZ, n_nodes - base);
    const int tid  = threadIdx.x;

    if (tid < RSZ) hist[tid] = 0;
    __syncthreads();

    const int s0 = colbase[r], s1 = colbase[r + 1];
    for (int j = s0 + tid; j < s1; j += 256)
        atomicAdd(&hist[ebuf[j] >> 16], 1);
    __syncthreads();

    if (tid < RSZ) {
        const int hv = hist[tid];
        int hc = hv;
        #pragma unroll
        for (int o = 1; o < 64; o <<= 1) {
            int u = __shfl_up(hc, o);
            if (tid >= o) hc += u;
        }
        const int start = s0 + hc - hv;   // exclusive within range
        cur[tid] = start;
        if (tid < lim) rsdeg[base + tid] = make_int2(start, hv);
    }
    __syncthreads();

    for (int j = s0 + tid; j < s1; j += 256) {
        const unsigned int p = ebuf[j];
        const int slot = atomicAdd(&cur[p >> 16], 1);
        csr[slot] = (unsigned short)p;     // src < 65536
    }
}

// ---------------------------------------------------------------------------
// Kernel E: gather = fused attention + aggregation + normalize + bias.
// One wave per node; edge ids in SGPRs (scalar-base gathers); exp2 domain.
// XCD-swizzled block mapping keeps contiguous csr windows on one XCD's L2.
// ---------------------------------------------------------------------------
__global__ __launch_bounds__(256) void gather_kernel(
    const unsigned short* __restrict__ proj,   // bf16
    const float* __restrict__ asrc,            // scaled
    const float* __restrict__ adst,            // scaled
    const int2* __restrict__ rsdeg,
    const unsigned short* __restrict__ csr,
    const float* __restrict__ bias,
    float* __restrict__ out,
    int n_nodes, int chunk)
{
    const int nb2 = (blockIdx.x & 7) * chunk + (blockIdx.x >> 3);
    const int n = nb2 * 4 + (threadIdx.x >> 6);
    if (n >= n_nodes) return;
    const int t = threadIdx.x & 63;
    const int h = t >> 4;

    const float ad = adst[n * HEADS + h];
    const float bv = bias[t];

    float z0 = asrc[n * HEADS + h] + ad;
    z0 = fmaxf(z0, NEG_SLOPE * z0);
    float s = exp2f(z0);
    float acc = s * bf2f(proj[(size_t)n * HID + t]);

    const int2 rd   = rsdeg[n];
    const int start = __builtin_amdgcn_readfirstlane(rd.x);
    const int d     = __builtin_amdgcn_readfirstlane(rd.y);
    const int end   = start + d;

    int j = start;
    for (; j + 8 <= end; j += 8) {
        int sid[8];
        #pragma unroll
        for (int k = 0; k < 8; ++k)
            sid[k] = __builtin_amdgcn_readfirstlane((int)csr[j + k]);
        float pv[8], av[8];
        #pragma unroll
        for (int k = 0; k < 8; ++k) pv[k] = bf2f(proj[sid[k] * HID + t]);
        #pragma unroll
        for (int k = 0; k < 8; ++k) av[k] = asrc[sid[k] * HEADS + h] + ad;
        #pragma unroll
        for (int k = 0; k < 8; ++k) {
            const float y = fmaxf(av[k], NEG_SLOPE * av[k]);
            const float e = exp2f(y);
            acc = fmaf(e, pv[k], acc);
            s += e;
        }
    }
    for (; j < end; ++j) {
        const int sj = __builtin_amdgcn_readfirstlane((int)csr[j]);
        const float pj = bf2f(proj[sj * HID + t]);
        float y = asrc[sj * HEADS + h] + ad;
        y = fmaxf(y, NEG_SLOPE * y);
        const float e = exp2f(y);
        acc = fmaf(e, pj, acc);
        s += e;
    }

    out[(size_t)n * HID + t] = acc / s + bv;
}

static inline size_t align16(size_t o) { return (o + 15) & ~(size_t)15; }

extern "C" void kernel_launch(void* const* d_in, const int* in_sizes, int n_in,
                              void* d_out, int out_size, void* d_ws, size_t ws_size,
                              hipStream_t stream)
{
    const float* x       = (const float*)d_in[0];
    const int*   ei      = (const int*)d_in[1];
    const float* W       = (const float*)d_in[2];
    const float* att_src = (const float*)d_in[3];
    const float* att_dst = (const float*)d_in[4];
    const float* bias    = (const float*)d_in[5];
    float* out           = (float*)d_out;

    const int n_nodes = in_sizes[0] / IN_CH;   // 50000
    const int n_edges = in_sizes[1] / 2;       // 1,000,000
    const int nblk    = (n_edges + SEG - 1) / SEG;       // 245
    const int nrange  = (n_nodes + RSZ - 1) / RSZ;       // 782
    const int nproj   = (n_nodes + 63) / 64;             // 782

    const int* src = ei;
    const int* dst = ei + n_edges;

    // ---- workspace layout ----
    char* base = (char*)d_ws;
    size_t o = 0;
    unsigned short* proj = (unsigned short*)(base + o); o = align16(o + (size_t)n_nodes * HID * 2);
    float* asrc      = (float*)(base + o); o = align16(o + (size_t)n_nodes * HEADS * 4);
    float* adst      = (float*)(base + o); o = align16(o + (size_t)n_nodes * HEADS * 4);
    int2*  rsdeg     = (int2*)(base + o);  o = align16(o + (size_t)n_nodes * 8);
    unsigned short* csr = (unsigned short*)(base + o); o = align16(o + (size_t)n_edges * 2);
    int*   cnt       = (int*)(base + o);   o = align16(o + (size_t)nblk * NRANGE * 4);
    int*   colbase   = (int*)(base + o);   o = align16(o + (NRANGE + 16) * 4);
    unsigned int* ebuf = (unsigned int*)(base + o); o = align16(o + (size_t)n_edges * 4);

    proj_count_kernel<<<nproj + nblk, 256, 0, stream>>>(
        x, W, att_src, att_dst, proj, asrc, adst, dst, cnt,
        n_nodes, n_edges, nproj);

    colprep_kernel<<<1, 1024, 0, stream>>>(cnt, colbase, nblk);

    bin_kernel<<<nblk, 256, 0, stream>>>(src, dst, cnt, colbase, ebuf, n_edges);

    range_csr_kernel<<<nrange, 256, 0, stream>>>(ebuf, colbase, rsdeg, csr, n_nodes);

    const int nb4   = (n_nodes + 3) / 4;                 // 12500
    const int chunk = (nb4 + 7) / 8;                     // 1563
    gather_kernel<<<chunk * 8, 256, 0, stream>>>(
        proj, asrc, adst, rsdeg, csr, bias, out, n_nodes, chunk);
}

// Round 13
// 197.801 us; speedup vs baseline: 1.3668x; 1.3668x over previous
//
#include <hip/hip_runtime.h>

#define IN_CH   128
#define HEADS   4
#define OUT_CH  16
#define HID     64
#define NEG_SLOPE 0.2f
#define LOG2E   1.44269504088896340736f

#define LDA 136            // padded LDS row stride in bf16 elems

// counting-sort config: destination ranges of 64 nodes
#define RB      6                  // log2(range size)
#define RSZ     64                 // nodes per destination range
#define NRANGE  1024               // padded range count (782 real for N=50000)
#define SEG     4096               // edges per sort block
// ebuf packing: (dlocal << 16) | src   — src < 2^16, dlocal < 2^6

typedef __attribute__((ext_vector_type(8))) short short8;     // 8 bf16
typedef __attribute__((ext_vector_type(4))) float float4v;    // 4 fp32 acc

__device__ __forceinline__ unsigned short f2bf(float f) {
    unsigned int u = __float_as_uint(f);
    u += 0x7FFFu + ((u >> 16) & 1u);
    return (unsigned short)(u >> 16);
}
__device__ __forceinline__ float bf2f(unsigned short u) {
    return __uint_as_float(((unsigned int)u) << 16);
}

// ---------------------------------------------------------------------------
// Kernel A (fused): blocks [0, nblk_proj) do proj GEMM; the rest histogram
// edge dests per segment into cnt[b][NRANGE]. asrc/adst are PRE-SCALED by
// log2(e) so gather can use native exp2 (identical math).
// ---------------------------------------------------------------------------
__global__ __launch_bounds__(256) void proj_count_kernel(
    const float* __restrict__ x,
    const float* __restrict__ W,
    const float* __restrict__ att_src,
    const float* __restrict__ att_dst,
    unsigned short* __restrict__ proj,   // [N, 64] bf16
    float* __restrict__ asrc,            // scaled by LOG2E
    float* __restrict__ adst,            // scaled by LOG2E
    const int* __restrict__ dst,
    int* __restrict__ cnt,
    int n_nodes, int n_edges, int nblk_proj)
{
    __shared__ unsigned short As[64 * LDA];
    __shared__ unsigned short Bs[64 * LDA];
    __shared__ int lc[NRANGE];

    const int tid = threadIdx.x;

    if (blockIdx.x >= nblk_proj) {
        // ---------------- count role ----------------
        const int b = blockIdx.x - nblk_proj;
        #pragma unroll
        for (int i = tid; i < NRANGE; i += 256) lc[i] = 0;
        __syncthreads();
        const int e0 = b * SEG;
        const int e1 = min(e0 + SEG, n_edges);
        for (int e = e0 + tid * 4; e < e1; e += 1024) {
            if (e + 4 <= e1) {
                const int4 d4 = *(const int4*)(dst + e);
                atomicAdd(&lc[d4.x >> RB], 1);
                atomicAdd(&lc[d4.y >> RB], 1);
                atomicAdd(&lc[d4.z >> RB], 1);
                atomicAdd(&lc[d4.w >> RB], 1);
            } else {
                for (int q = e; q < e1; ++q) atomicAdd(&lc[dst[q] >> RB], 1);
            }
        }
        __syncthreads();
        #pragma unroll
        for (int i = tid; i < NRANGE; i += 256) cnt[b * NRANGE + i] = lc[i];
        return;
    }

    // ---------------- proj role ----------------
    const int n0 = blockIdx.x * 64;

    #pragma unroll
    for (int i = 0; i < 8; ++i) {
        int idx4 = i * 256 + tid;
        int row  = idx4 >> 5;
        int c4   = (idx4 & 31) * 4;
        float4 v = *(const float4*)(W + row * IN_CH + c4);
        ushort4 o;
        o.x = f2bf(v.x); o.y = f2bf(v.y); o.z = f2bf(v.z); o.w = f2bf(v.w);
        *(ushort4*)(&Bs[row * LDA + c4]) = o;
    }
    #pragma unroll
    for (int i = 0; i < 8; ++i) {
        int idx4 = i * 256 + tid;
        int row  = idx4 >> 5;
        int c4   = (idx4 & 31) * 4;
        int n    = n0 + row;
        float4 v = make_float4(0.f, 0.f, 0.f, 0.f);
        if (n < n_nodes) v = *(const float4*)(x + (size_t)n * IN_CH + c4);
        ushort4 o;
        o.x = f2bf(v.x); o.y = f2bf(v.y); o.z = f2bf(v.z); o.w = f2bf(v.w);
        *(ushort4*)(&As[row * LDA + c4]) = o;
    }
    __syncthreads();

    const int w    = tid >> 6;
    const int lane = tid & 63;
    const int l16  = lane & 15;
    const int quad = lane >> 4;

    float4v acc0 = {0.f,0.f,0.f,0.f};
    float4v acc1 = {0.f,0.f,0.f,0.f};
    float4v acc2 = {0.f,0.f,0.f,0.f};
    float4v acc3 = {0.f,0.f,0.f,0.f};

    const unsigned short* arow = &As[(w * 16 + l16) * LDA + quad * 8];
    const unsigned short* b0   = &Bs[( 0 + l16) * LDA + quad * 8];
    const unsigned short* b1   = &Bs[(16 + l16) * LDA + quad * 8];
    const unsigned short* b2   = &Bs[(32 + l16) * LDA + quad * 8];
    const unsigned short* b3   = &Bs[(48 + l16) * LDA + quad * 8];

    #pragma unroll
    for (int k0 = 0; k0 < IN_CH; k0 += 32) {
        short8 a  = *(const short8*)(arow + k0);
        acc0 = __builtin_amdgcn_mfma_f32_16x16x32_bf16(a, *(const short8*)(b0 + k0), acc0, 0, 0, 0);
        acc1 = __builtin_amdgcn_mfma_f32_16x16x32_bf16(a, *(const short8*)(b1 + k0), acc1, 0, 0, 0);
        acc2 = __builtin_amdgcn_mfma_f32_16x16x32_bf16(a, *(const short8*)(b2 + k0), acc2, 0, 0, 0);
        acc3 = __builtin_amdgcn_mfma_f32_16x16x32_bf16(a, *(const short8*)(b3 + k0), acc3, 0, 0, 0);
    }

    const float as0 = att_src[ 0 + l16], ad0 = att_dst[ 0 + l16];
    const float as1 = att_src[16 + l16], ad1 = att_dst[16 + l16];
    const float as2 = att_src[32 + l16], ad2 = att_dst[32 + l16];
    const float as3 = att_src[48 + l16], ad3 = att_dst[48 + l16];

    #pragma unroll
    for (int r = 0; r < 4; ++r) {
        const int n = n0 + w * 16 + quad * 4 + r;
        const bool ok = (n < n_nodes);
        float v0 = acc0[r], v1 = acc1[r], v2 = acc2[r], v3 = acc3[r];
        if (ok) {
            proj[(size_t)n * HID +  0 + l16] = f2bf(v0);
            proj[(size_t)n * HID + 16 + l16] = f2bf(v1);
            proj[(size_t)n * HID + 32 + l16] = f2bf(v2);
            proj[(size_t)n * HID + 48 + l16] = f2bf(v3);
        }
        float s0 = v0 * as0, s1 = v1 * as1, s2 = v2 * as2, s3 = v3 * as3;
        float d0 = v0 * ad0, d1 = v1 * ad1, d2 = v2 * ad2, d3 = v3 * ad3;
        #pragma unroll
        for (int off = 8; off >= 1; off >>= 1) {
            s0 += __shfl_down(s0, off, 16);
            s1 += __shfl_down(s1, off, 16);
            s2 += __shfl_down(s2, off, 16);
            s3 += __shfl_down(s3, off, 16);
            d0 += __shfl_down(d0, off, 16);
            d1 += __shfl_down(d1, off, 16);
            d2 += __shfl_down(d2, off, 16);
            d3 += __shfl_down(d3, off, 16);
        }
        if (ok && l16 == 0) {
            asrc[n * HEADS + 0] = s0 * LOG2E;
            asrc[n * HEADS + 1] = s1 * LOG2E;
            asrc[n * HEADS + 2] = s2 * LOG2E;
            asrc[n * HEADS + 3] = s3 * LOG2E;
            adst[n * HEADS + 0] = d0 * LOG2E;
            adst[n * HEADS + 1] = d1 * LOG2E;
            adst[n * HEADS + 2] = d2 * LOG2E;
            adst[n * HEADS + 3] = d3 * LOG2E;
        }
    }
}

// ---------------------------------------------------------------------------
// Kernel B: colprep — per-range totals (coalesced column sums over cnt) +
// block-wide exclusive scan -> colbase[NRANGE+1]. One block, 1024 threads.
// ---------------------------------------------------------------------------
__global__ __launch_bounds__(1024) void colprep_kernel(
    const int* __restrict__ cnt, int* __restrict__ colbase, int nblk)
{
    __shared__ int wtot[16];
    const int r = threadIdx.x;           // 0..1023 = range id
    int tot = 0;
    for (int b = 0; b < nblk; ++b) tot += cnt[b * NRANGE + r];
    const int lane = r & 63;
    const int wv   = r >> 6;
    int sc = tot;
    #pragma unroll
    for (int o = 1; o < 64; o <<= 1) {
        int u = __shfl_up(sc, o);
        if (lane >= o) sc += u;
    }
    if (lane == 63) wtot[wv] = sc;
    __syncthreads();
    int add = 0;
    for (int w = 0; w < wv; ++w) add += wtot[w];
    colbase[r] = add + sc - tot;         // exclusive
    if (r == NRANGE - 1) colbase[NRANGE] = add + sc;
}

// ---------------------------------------------------------------------------
// Kernel C: colscan — per-column prefix over segment blocks -> off[b][r].
// One wave per range (1024 blocks); 4 shuffle-scan rounds over 245 blocks.
// ---------------------------------------------------------------------------
__global__ __launch_bounds__(64) void colscan_kernel(
    const int* __restrict__ cnt, const int* __restrict__ colbase,
    int* __restrict__ off, int nblk)
{
    const int r = blockIdx.x;
    const int l = threadIdx.x;
    int carry = colbase[r];
    for (int c0 = 0; c0 < nblk; c0 += 64) {
        const int b = c0 + l;
        int v = (b < nblk) ? cnt[b * NRANGE + r] : 0;
        int p = v;
        #pragma unroll
        for (int o = 1; o < 64; o <<= 1) {
            int u = __shfl_up(p, o);
            if (l >= o) p += u;
        }
        if (b < nblk) off[b * NRANGE + r] = carry + p - v;
        carry += __shfl(p, 63);
    }
}

// ---------------------------------------------------------------------------
// Kernel D: bin edges into range-major ebuf, packed (dlocal<<16)|src.
// lpos loaded directly from precomputed off.
// ---------------------------------------------------------------------------
__global__ __launch_bounds__(256) void bin_kernel(
    const int* __restrict__ src, const int* __restrict__ dst,
    const int* __restrict__ off, unsigned int* __restrict__ ebuf, int n_edges)
{
    __shared__ int lpos[NRANGE];
    const int b = blockIdx.x;
    const int t = threadIdx.x;

    #pragma unroll
    for (int c = t; c < NRANGE; c += 256) lpos[c] = off[b * NRANGE + c];
    __syncthreads();

    const int e0 = b * SEG;
    const int e1 = min(e0 + SEG, n_edges);
    for (int e = e0 + t * 4; e < e1; e += 1024) {
        if (e + 4 <= e1) {
            const int4 s4 = *(const int4*)(src + e);
            const int4 d4 = *(const int4*)(dst + e);
            {
                const int slot = atomicAdd(&lpos[d4.x >> RB], 1);
                ebuf[slot] = ((unsigned int)(d4.x & (RSZ - 1)) << 16) | (unsigned int)s4.x;
            }
            {
                const int slot = atomicAdd(&lpos[d4.y >> RB], 1);
                ebuf[slot] = ((unsigned int)(d4.y & (RSZ - 1)) << 16) | (unsigned int)s4.y;
            }
            {
                const int slot = atomicAdd(&lpos[d4.z >> RB], 1);
                ebuf[slot] = ((unsigned int)(d4.z & (RSZ - 1)) << 16) | (unsigned int)s4.z;
            }
            {
                const int slot = atomicAdd(&lpos[d4.w >> RB], 1);
                ebuf[slot] = ((unsigned int)(d4.w & (RSZ - 1)) << 16) | (unsigned int)s4.w;
            }
        } else {
            for (int q = e; q < e1; ++q) {
                const int d = dst[q];
                const int slot = atomicAdd(&lpos[d >> RB], 1);
                ebuf[slot] = ((unsigned int)(d & (RSZ - 1)) << 16) | (unsigned int)src[q];
            }
        }
    }
}

// ---------------------------------------------------------------------------
// Kernel E: per-range (64-node) histogram + single-wave scan + rsdeg write +
// LDS-atomic scatter into the range's csr window. One block per range (782).
// ---------------------------------------------------------------------------
__global__ __launch_bounds__(256) void range_csr_kernel(
    const unsigned int* __restrict__ ebuf, const int* __restrict__ colbase,
    int2* __restrict__ rsdeg, unsigned short* __restrict__ csr, int n_nodes)
{
    __shared__ int hist[RSZ];
    __shared__ int cur[RSZ];

    const int r    = blockIdx.x;
    const int base = r << RB;
    const int lim  = min(RSZ, n_nodes - base);
    const int tid  = threadIdx.x;

    if (tid < RSZ) hist[tid] = 0;
    __syncthreads();

    const int s0 = colbase[r], s1 = colbase[r + 1];
    for (int j = s0 + tid; j < s1; j += 256)
        atomicAdd(&hist[ebuf[j] >> 16], 1);
    __syncthreads();

    if (tid < RSZ) {
        const int hv = hist[tid];
        int hc = hv;
        #pragma unroll
        for (int o = 1; o < 64; o <<= 1) {
            int u = __shfl_up(hc, o);
            if (tid >= o) hc += u;
        }
        const int start = s0 + hc - hv;   // exclusive within range
        cur[tid] = start;
        if (tid < lim) rsdeg[base + tid] = make_int2(start, hv);
    }
    __syncthreads();

    for (int j = s0 + tid; j < s1; j += 256) {
        const unsigned int p = ebuf[j];
        const int slot = atomicAdd(&cur[p >> 16], 1);
        csr[slot] = (unsigned short)p;     // src < 65536
    }
}

// ---------------------------------------------------------------------------
// Kernel F: gather = fused attention + aggregation + normalize + bias.
// One wave per node; edge ids in SGPRs (scalar-base gathers); exp2 domain.
// XCD-swizzled block mapping keeps contiguous csr windows on one XCD's L2.
// ---------------------------------------------------------------------------
__global__ __launch_bounds__(256) void gather_kernel(
    const unsigned short* __restrict__ proj,   // bf16
    const float* __restrict__ asrc,            // scaled
    const float* __restrict__ adst,            // scaled
    const int2* __restrict__ rsdeg,
    const unsigned short* __restrict__ csr,
    const float* __restrict__ bias,
    float* __restrict__ out,
    int n_nodes, int chunk)
{
    const int nb2 = (blockIdx.x & 7) * chunk + (blockIdx.x >> 3);
    const int n = nb2 * 4 + (threadIdx.x >> 6);
    if (n >= n_nodes) return;
    const int t = threadIdx.x & 63;
    const int h = t >> 4;

    const float ad = adst[n * HEADS + h];
    const float bv = bias[t];

    float z0 = asrc[n * HEADS + h] + ad;
    z0 = fmaxf(z0, NEG_SLOPE * z0);
    float s = exp2f(z0);
    float acc = s * bf2f(proj[(size_t)n * HID + t]);

    const int2 rd   = rsdeg[n];
    const int start = __builtin_amdgcn_readfirstlane(rd.x);
    const int d     = __builtin_amdgcn_readfirstlane(rd.y);
    const int end   = start + d;

    int j = start;
    for (; j + 8 <= end; j += 8) {
        int sid[8];
        #pragma unroll
        for (int k = 0; k < 8; ++k)
            sid[k] = __builtin_amdgcn_readfirstlane((int)csr[j + k]);
        float pv[8], av[8];
        #pragma unroll
        for (int k = 0; k < 8; ++k) pv[k] = bf2f(proj[sid[k] * HID + t]);
        #pragma unroll
        for (int k = 0; k < 8; ++k) av[k] = asrc[sid[k] * HEADS + h] + ad;
        #pragma unroll
        for (int k = 0; k < 8; ++k) {
            const float y = fmaxf(av[k], NEG_SLOPE * av[k]);
            const float e = exp2f(y);
            acc = fmaf(e, pv[k], acc);
            s += e;
        }
    }
    for (; j < end; ++j) {
        const int sj = __builtin_amdgcn_readfirstlane((int)csr[j]);
        const float pj = bf2f(proj[sj * HID + t]);
        float y = asrc[sj * HEADS + h] + ad;
        y = fmaxf(y, NEG_SLOPE * y);
        const float e = exp2f(y);
        acc = fmaf(e, pj, acc);
        s += e;
    }

    out[(size_t)n * HID + t] = acc / s + bv;
}

static inline size_t align16(size_t o) { return (o + 15) & ~(size_t)15; }

extern "C" void kernel_launch(void* const* d_in, const int* in_sizes, int n_in,
                              void* d_out, int out_size, void* d_ws, size_t ws_size,
                              hipStream_t stream)
{
    const float* x       = (const float*)d_in[0];
    const int*   ei      = (const int*)d_in[1];
    const float* W       = (const float*)d_in[2];
    const float* att_src = (const float*)d_in[3];
    const float* att_dst = (const float*)d_in[4];
    const float* bias    = (const float*)d_in[5];
    float* out           = (float*)d_out;

    const int n_nodes = in_sizes[0] / IN_CH;   // 50000
    const int n_edges = in_sizes[1] / 2;       // 1,000,000
    const int nblk    = (n_edges + SEG - 1) / SEG;       // 245
    const int nrange  = (n_nodes + RSZ - 1) / RSZ;       // 782
    const int nproj   = (n_nodes + 63) / 64;             // 782

    const int* src = ei;
    const int* dst = ei + n_edges;

    // ---- workspace layout ----
    char* base = (char*)d_ws;
    size_t o = 0;
    unsigned short* proj = (unsigned short*)(base + o); o = align16(o + (size_t)n_nodes * HID * 2);
    float* asrc      = (float*)(base + o); o = align16(o + (size_t)n_nodes * HEADS * 4);
    float* adst      = (float*)(base + o); o = align16(o + (size_t)n_nodes * HEADS * 4);
    int2*  rsdeg     = (int2*)(base + o);  o = align16(o + (size_t)n_nodes * 8);
    unsigned short* csr = (unsigned short*)(base + o); o = align16(o + (size_t)n_edges * 2);
    int*   cnt       = (int*)(base + o);   o = align16(o + (size_t)nblk * NRANGE * 4);
    int*   off       = (int*)(base + o);   o = align16(o + (size_t)nblk * NRANGE * 4);
    int*   colbase   = (int*)(base + o);   o = align16(o + (NRANGE + 16) * 4);
    unsigned int* ebuf = (unsigned int*)(base + o); o = align16(o + (size_t)n_edges * 4);

    proj_count_kernel<<<nproj + nblk, 256, 0, stream>>>(
        x, W, att_src, att_dst, proj, asrc, adst, dst, cnt,
        n_nodes, n_edges, nproj);

    colprep_kernel<<<1, 1024, 0, stream>>>(cnt, colbase, nblk);

    colscan_kernel<<<NRANGE, 64, 0, stream>>>(cnt, colbase, off, nblk);

    bin_kernel<<<nblk, 256, 0, stream>>>(src, dst, off, ebuf, n_edges);

    range_csr_kernel<<<nrange, 256, 0, stream>>>(ebuf, colbase, rsdeg, csr, n_nodes);

    const int nb4   = (n_nodes + 3) / 4;                 // 12500
    const int chunk = (nb4 + 7) / 8;                     // 1563
    gather_kernel<<<chunk * 8, 256, 0, stream>>>(
        proj, asrc, adst, rsdeg, csr, bias, out, n_nodes, chunk);
}